// Round 3
// baseline (513.040 us; speedup 1.0000x reference)
//
#include <hip/hip_runtime.h>

// Problem constants (reference: x [64,256,64,64] fp32, keep_num=2048)
#define BB 64
#define CC 256
#define NN 4096          // 64*64 tokens
#define KKEEP 2048
#define CCHUNK 64        // channel chunk per partial-score phase (4 chunks)
#define NBLK 512
#define TPB 256

// ---------------------------------------------------------------------------
// Hand-rolled grid barrier (hipLaunchCooperativeKernel is NOT capturable by
// the harness's graph capture -- verified R2: all-zero output signature).
// Safety:
//  * residency: __launch_bounds__(256,4) caps VGPR<=128, LDS ~1.2KB -> >=2
//    blocks/CU guaranteed -> 512 blocks always co-resident (2x margin at the
//    expected 4/CU).
//  * coherence: __syncthreads drains vmcnt (stores reach L2); agent-scope
//    release fence writes back the XCD L2 (buffer_wbl2); waiter does a
//    relaxed poll then agent-scope acquire fence (buffer_inv) so post-barrier
//    reads miss to L3/HBM fresh.  Counters are zeroed per-iteration by a
//    capture-safe hipMemsetAsync (the harness itself records memsets).
//  * no-hang failsafe: bounded spin (~4M polls) -> wrong answer, not timeout.
// ---------------------------------------------------------------------------
__device__ __forceinline__ void grid_barrier(unsigned* cnt, int t) {
    __syncthreads();
    if (t == 0) {
        __threadfence();  // release: flush this block's stores out of XCD L2
        __hip_atomic_fetch_add(cnt, 1u, __ATOMIC_RELEASE, __HIP_MEMORY_SCOPE_AGENT);
        unsigned spins = 0;
        while (__hip_atomic_load(cnt, __ATOMIC_RELAXED, __HIP_MEMORY_SCOPE_AGENT) < NBLK) {
            __builtin_amdgcn_s_sleep(2);
            if (++spins > (1u << 22)) break;   // failsafe: never deadlock
        }
        __threadfence();  // acquire: invalidate local caches
    }
    __syncthreads();
}

// ---------------------------------------------------------------------------
// Fused kernel: score -> barrier -> select -> barrier -> pool.
// 512 blocks x 256 threads (2 work-units per block vs the 1024-unit mapping).
// Phase 3 walks rows in REVERSE phase-1 read-time order: x is 256 MiB =
// exactly the Infinity-Cache size, so the tail of phase 1's stream is still
// L3-resident when phase 3 starts (LIFO anti-thrash).
// ---------------------------------------------------------------------------
__global__ __launch_bounds__(TPB, 4) void fused_kernel(
    const float* __restrict__ x, float* __restrict__ P,
    float* __restrict__ M, float* __restrict__ out, unsigned* __restrict__ cnt) {
    const int bid = blockIdx.x;
    const int t   = threadIdx.x;

    // ---------------- Phase 1: partial token scores ----------------
    // P[cy][b][n] = sum_{c in chunk cy} |x[b,c,n]|
    #pragma unroll
    for (int r = 0; r < 2; ++r) {
        const int u  = bid * 2 + r;       // 0..1023 work units
        const int cy = u >> 8;            // channel chunk
        const int b  = (u & 255) >> 2;    // batch
        const int ng = u & 3;             // token group
        const int n0 = ng * 1024 + t * 4;
        const float* xb = x + (size_t)(b * CC + cy * CCHUNK) * NN + n0;
        float4 acc = make_float4(0.f, 0.f, 0.f, 0.f);
        #pragma unroll 8
        for (int c = 0; c < CCHUNK; ++c) {
            const float4 v = *(const float4*)(xb + (size_t)c * NN);
            acc.x += fabsf(v.x); acc.y += fabsf(v.y);
            acc.z += fabsf(v.z); acc.w += fabsf(v.w);
        }
        *(float4*)(P + (size_t)(cy * BB + b) * NN + n0) = acc;
    }

    grid_barrier(cnt + 0, t);

    // ---------------- Phase 2: top-k selection -> 0/1 mask ----------------
    // Blocks 0..63, one per batch.  Identical to the verified select kernel:
    // greedy bit-build on uint32-ordered fp32 bit patterns (scores >= 0),
    // block-max free reject, exact-count early exit, jax-compatible tie-break.
    if (bid < BB) {
        const int b = bid;
        __shared__ unsigned wred[2][4];
        __shared__ unsigned cnts[256];

        const float* p0 = P + (size_t)(0 * BB + b) * NN;
        const float* p1 = P + (size_t)(1 * BB + b) * NN;
        const float* p2 = P + (size_t)(2 * BB + b) * NN;
        const float* p3 = P + (size_t)(3 * BB + b) * NN;
        const int base = t * 16;

        unsigned su[16];
        #pragma unroll
        for (int j = 0; j < 16; j += 4) {
            float4 a0 = *(const float4*)(p0 + base + j);
            float4 a1 = *(const float4*)(p1 + base + j);
            float4 a2 = *(const float4*)(p2 + base + j);
            float4 a3 = *(const float4*)(p3 + base + j);
            su[j + 0] = __float_as_uint(a0.x + a1.x + a2.x + a3.x);
            su[j + 1] = __float_as_uint(a0.y + a1.y + a2.y + a3.y);
            su[j + 2] = __float_as_uint(a0.z + a1.z + a2.z + a3.z);
            su[j + 3] = __float_as_uint(a0.w + a1.w + a2.w + a3.w);
        }

        int slot = 0;
        // ONE barrier per round, double-buffered (round-(r+2) write can't
        // pass the round-(r+1) barrier before all round-r reads are done).
        auto reduce_add = [&](unsigned v) -> unsigned {
            #pragma unroll
            for (int off = 32; off; off >>= 1) v += __shfl_down(v, off, 64);
            if ((t & 63) == 0) wred[slot][t >> 6] = v;
            __syncthreads();
            unsigned tot = wred[slot][0] + wred[slot][1] + wred[slot][2] + wred[slot][3];
            slot ^= 1;
            return tot;
        };
        auto count_ge = [&](unsigned thr) -> unsigned {
            unsigned c = 0;
            #pragma unroll
            for (int j = 0; j < 16; ++j) c += (su[j] >= thr) ? 1u : 0u;
            return reduce_add(c);
        };

        unsigned lmax = 0;
        #pragma unroll
        for (int j = 0; j < 16; ++j) lmax = (su[j] > lmax) ? su[j] : lmax;
        {
            unsigned v = lmax;
            #pragma unroll
            for (int off = 32; off; off >>= 1) {
                unsigned w = __shfl_down(v, off, 64);
                v = (w > v) ? w : v;
            }
            if ((t & 63) == 0) wred[slot][t >> 6] = v;
            __syncthreads();
            unsigned m01 = (wred[slot][0] > wred[slot][1]) ? wred[slot][0] : wred[slot][1];
            unsigned m23 = (wred[slot][2] > wred[slot][3]) ? wred[slot][2] : wred[slot][3];
            lmax = (m01 > m23) ? m01 : m23;
            slot ^= 1;
        }
        const unsigned mx = lmax;

        float* mb = M + (size_t)b * NN + base;

        unsigned T = 0;
        bool done = false;
        for (int bit = 31; bit >= 0; --bit) {
            const unsigned cand = T | (1u << bit);
            if (cand > mx) continue;               // free reject
            const unsigned c = count_ge(cand);
            if (c >= KKEEP) {
                T = cand;
                if (c == KKEEP) { done = true; break; }
            }
        }

        if (done) {
            #pragma unroll
            for (int j = 0; j < 16; ++j) mb[j] = (su[j] >= T) ? 1.0f : 0.0f;
        } else {
            const unsigned cnt_gt = count_ge(T + 1u);
            const unsigned need_eq = KKEEP - cnt_gt;

            unsigned local_eq = 0;
            #pragma unroll
            for (int j = 0; j < 16; ++j) local_eq += (su[j] == T) ? 1u : 0u;
            cnts[t] = local_eq;
            __syncthreads();
            unsigned prefix = 0;
            for (int p = 0; p < t; ++p) prefix += cnts[p];

            unsigned run = prefix;
            #pragma unroll
            for (int j = 0; j < 16; ++j) {
                bool sel;
                if (su[j] > T)       sel = true;
                else if (su[j] == T) { sel = (run < need_eq); ++run; }
                else                 sel = false;
                mb[j] = sel ? 1.0f : 0.0f;
            }
        }
    }

    grid_barrier(cnt + 16, t);   // separate cacheline-ish slot

    // ---------------- Phase 3: masked mean over tokens ----------------
    // out[b][c] = (1/2048) * sum_n M[b][n] * x[b][c][n]
    // 2048 waves x 2 units; each unit = 4 consecutive channel rows sharing
    // one mask float4 per j-step; rows walked in reverse phase-1 order.
    {
        const int wave = t >> 6;
        const int lane = t & 63;
        const int gw   = (bid << 2) | wave;       // 0..2047
        const float s  = 1.0f / 2048.0f;
        #pragma unroll
        for (int r = 0; r < 2; ++r) {
            const int u   = gw * 2 + r;           // 0..4095 units
            const int inv = 4095 - u;             // reverse phase-1 read order
            const int cyk = inv >> 10;
            const int rem = inv & 1023;
            const int bk  = rem >> 4;
            const int cb  = rem & 15;
            const int row0 = bk * CC + cyk * CCHUNK + cb * 4;
            const float* xr = x + (size_t)row0 * NN;
            const float* mr = M + (size_t)bk * NN;
            float a0 = 0.f, a1 = 0.f, a2 = 0.f, a3 = 0.f;
            #pragma unroll 4
            for (int j = 0; j < 16; ++j) {
                const int n = j * 256 + lane * 4;
                const float4 m  = *(const float4*)(mr + n);   // shared by 4 rows
                const float4 v0 = *(const float4*)(xr + n);
                const float4 v1 = *(const float4*)(xr + (size_t)NN + n);
                const float4 v2 = *(const float4*)(xr + (size_t)2 * NN + n);
                const float4 v3 = *(const float4*)(xr + (size_t)3 * NN + n);
                a0 += v0.x * m.x + v0.y * m.y + v0.z * m.z + v0.w * m.w;
                a1 += v1.x * m.x + v1.y * m.y + v1.z * m.z + v1.w * m.w;
                a2 += v2.x * m.x + v2.y * m.y + v2.z * m.z + v2.w * m.w;
                a3 += v3.x * m.x + v3.y * m.y + v3.z * m.z + v3.w * m.w;
            }
            #pragma unroll
            for (int off = 32; off; off >>= 1) {
                a0 += __shfl_down(a0, off, 64);
                a1 += __shfl_down(a1, off, 64);
                a2 += __shfl_down(a2, off, 64);
                a3 += __shfl_down(a3, off, 64);
            }
            if (lane == 0) {
                *(float4*)(out + row0) = make_float4(a0 * s, a1 * s, a2 * s, a3 * s);
            }
        }
    }
}

extern "C" void kernel_launch(void* const* d_in, const int* in_sizes, int n_in,
                              void* d_out, int out_size, void* d_ws, size_t ws_size,
                              hipStream_t stream) {
    const float* x = (const float*)d_in[0];
    float* out = (float*)d_out;
    // ws layout: P = [4][64][4096] fp32 (4 MB), M = [64][4096] fp32 (1 MB),
    // cnt = 32 unsigned barrier counters (zeroed each iteration below, so the
    // harness 0xAA re-poison is harmless; P/M are written before being read).
    float* P = (float*)d_ws;
    float* M = P + (size_t)4 * BB * NN;
    unsigned* cnt = (unsigned*)(M + (size_t)BB * NN);

    hipMemsetAsync(cnt, 0, 32 * sizeof(unsigned), stream);
    hipLaunchKernelGGL(fused_kernel, dim3(NBLK), dim3(TPB), 0, stream,
                       x, P, M, out, cnt);
}

// Round 4
// 420.862 us; speedup vs baseline: 1.2190x; 1.2190x over previous
//
#include <hip/hip_runtime.h>

// Problem constants (reference: x [64,256,64,64] fp32, keep_num=2048)
#define BB 64
#define CC 256
#define NN 4096          // 64*64 tokens
#define KKEEP 2048
#define NCHUNK 8         // channel chunks
#define CCHUNK 32        // channels per chunk (8 x 32 = 256)

// ---------------------------------------------------------------------------
// Kernel 1: partial token scores.  P[cy][b][n] = sum_{c in chunk cy} |x[b,c,n]|
// grid = (B*4, 8)  block = 256, __launch_bounds__(256,8) -> VGPR<=64 ->
// 8 blocks/CU = 32 waves/CU (was 16 at 64-ch chunks).  x is HBM-cold here
// (the harness's 1 GiB workspace poison evicts L3 every iteration -- proven
// R3: fused FETCH = 267 MB = exactly one pass), so this pass needs maximum
// latency hiding.  Coalesced float4: 1 KiB/wave/instr.
// ---------------------------------------------------------------------------
__global__ __launch_bounds__(256, 8) void score_partial_kernel(
    const float* __restrict__ x, float* __restrict__ P) {
    const int b  = blockIdx.x >> 2;
    const int ng = blockIdx.x & 3;
    const int cy = blockIdx.y;
    const int n0 = ng * 1024 + threadIdx.x * 4;
    const float* xb = x + (size_t)(b * CC + cy * CCHUNK) * NN + n0;
    float4 acc = make_float4(0.f, 0.f, 0.f, 0.f);
    #pragma unroll 8
    for (int c = 0; c < CCHUNK; ++c) {
        const float4 v = *(const float4*)(xb + (size_t)c * NN);
        acc.x += fabsf(v.x); acc.y += fabsf(v.y);
        acc.z += fabsf(v.z); acc.w += fabsf(v.w);
    }
    *(float4*)(P + (size_t)(cy * BB + b) * NN + n0) = acc;
}

// ---------------------------------------------------------------------------
// Kernel 2: per-batch top-k selection -> 0/1 float mask (verified algorithm).
// One block per batch, 256 threads, thread t owns tokens [16t,16t+16).
// Scores >= 0 -> fp32 bits are uint32-order-isomorphic; greedy bit-build
// finds the kth-largest pattern T.  Block-max free reject + exact-count
// early exit; tie-break matches jax.lax.top_k (lowest index first).
// ---------------------------------------------------------------------------
__global__ __launch_bounds__(256) void select_kernel(
    const float* __restrict__ P, float* __restrict__ M) {
    const int b = blockIdx.x;
    const int t = threadIdx.x;
    __shared__ unsigned wred[2][4];
    __shared__ unsigned cnts[256];

    const int base = t * 16;
    unsigned su[16];
    #pragma unroll
    for (int j = 0; j < 16; j += 4) {
        float4 s = make_float4(0.f, 0.f, 0.f, 0.f);
        #pragma unroll
        for (int cy = 0; cy < NCHUNK; ++cy) {
            const float4 a = *(const float4*)(P + (size_t)(cy * BB + b) * NN + base + j);
            s.x += a.x; s.y += a.y; s.z += a.z; s.w += a.w;
        }
        su[j + 0] = __float_as_uint(s.x);
        su[j + 1] = __float_as_uint(s.y);
        su[j + 2] = __float_as_uint(s.z);
        su[j + 3] = __float_as_uint(s.w);
    }

    int slot = 0;
    // ONE barrier per round, double-buffered (a thread reaches the
    // round-(r+2) write only after the round-(r+1) barrier, which all
    // threads pass only after their round-r read of the other buffer).
    auto reduce_add = [&](unsigned v) -> unsigned {
        #pragma unroll
        for (int off = 32; off; off >>= 1) v += __shfl_down(v, off, 64);
        if ((t & 63) == 0) wred[slot][t >> 6] = v;
        __syncthreads();
        unsigned tot = wred[slot][0] + wred[slot][1] + wred[slot][2] + wred[slot][3];
        slot ^= 1;
        return tot;
    };
    auto count_ge = [&](unsigned thr) -> unsigned {
        unsigned c = 0;
        #pragma unroll
        for (int j = 0; j < 16; ++j) c += (su[j] >= thr) ? 1u : 0u;
        return reduce_add(c);
    };

    unsigned lmax = 0;
    #pragma unroll
    for (int j = 0; j < 16; ++j) lmax = (su[j] > lmax) ? su[j] : lmax;
    {
        unsigned v = lmax;
        #pragma unroll
        for (int off = 32; off; off >>= 1) {
            unsigned w = __shfl_down(v, off, 64);
            v = (w > v) ? w : v;
        }
        if ((t & 63) == 0) wred[slot][t >> 6] = v;
        __syncthreads();
        unsigned m01 = (wred[slot][0] > wred[slot][1]) ? wred[slot][0] : wred[slot][1];
        unsigned m23 = (wred[slot][2] > wred[slot][3]) ? wred[slot][2] : wred[slot][3];
        lmax = (m01 > m23) ? m01 : m23;
        slot ^= 1;
    }
    const unsigned mx = lmax;

    float* mb = M + (size_t)b * NN + base;

    unsigned T = 0;
    bool done = false;
    for (int bit = 31; bit >= 0; --bit) {
        const unsigned cand = T | (1u << bit);
        if (cand > mx) continue;               // free reject: no value >= cand
        const unsigned c = count_ge(cand);
        if (c >= KKEEP) {
            T = cand;
            if (c == KKEEP) { done = true; break; }  // set uniquely determined
        }
    }

    if (done) {
        #pragma unroll
        for (int j = 0; j < 16; ++j) mb[j] = (su[j] >= T) ? 1.0f : 0.0f;
        return;
    }

    // Tie path (exact collisions at the threshold): keep lowest indices first.
    const unsigned cnt_gt = count_ge(T + 1u);
    const unsigned need_eq = KKEEP - cnt_gt;

    unsigned local_eq = 0;
    #pragma unroll
    for (int j = 0; j < 16; ++j) local_eq += (su[j] == T) ? 1u : 0u;
    cnts[t] = local_eq;
    __syncthreads();
    unsigned prefix = 0;
    for (int p = 0; p < t; ++p) prefix += cnts[p];

    unsigned run = prefix;
    #pragma unroll
    for (int j = 0; j < 16; ++j) {
        bool sel;
        if (su[j] > T)       sel = true;
        else if (su[j] == T) { sel = (run < need_eq); ++run; }
        else                 sel = false;
        mb[j] = sel ? 1.0f : 0.0f;
    }
}

// ---------------------------------------------------------------------------
// Kernel 3: out[b][c] = (1/2048) * sum_n M[b][n] * x[b][c][n]
// 1024 blocks x 4 waves; each wave owns 4 consecutive channel rows: the mask
// float4 is loaded ONCE per j-step and reused for 4 x-rows, and the 4 outputs
// store as one float4.  Rows are walked in REVERSE kernel-1 read-time order
// (cy outer desc, b desc, c desc): x is 256 MiB = exactly the Infinity-Cache
// size, so k1's stream tail is still L3-resident -- PROVEN R3 (fused-kernel
// FETCH = 267 MB = one pass for the whole two-pass algorithm).
// ---------------------------------------------------------------------------
__global__ __launch_bounds__(256) void pool_kernel(
    const float* __restrict__ x, const float* __restrict__ M,
    float* __restrict__ out) {
    const int wave = threadIdx.x >> 6;
    const int lane = threadIdx.x & 63;
    const int u    = (blockIdx.x << 2) | wave;   // 0..4095 units of 4 rows
    const int inv  = 4095 - u;                   // reverse k1 read-time order
    const int cyk  = inv >> 9;                   // k1 chunk (outer in time), 0..7
    const int rem  = inv & 511;
    const int bk   = rem >> 3;                   // k1 batch (inner in time)
    const int cb   = rem & 7;                    // 4-channel group within chunk
    const int row0 = bk * CC + cyk * CCHUNK + cb * 4;
    const float* xr = x + (size_t)row0 * NN;
    const float* mr = M + (size_t)bk * NN;
    float a0 = 0.f, a1 = 0.f, a2 = 0.f, a3 = 0.f;
    #pragma unroll 4
    for (int j = 0; j < 16; ++j) {
        const int n = j * 256 + lane * 4;
        const float4 m  = *(const float4*)(mr + n);   // shared by 4 rows
        const float4 v0 = *(const float4*)(xr + n);
        const float4 v1 = *(const float4*)(xr + (size_t)NN + n);
        const float4 v2 = *(const float4*)(xr + (size_t)2 * NN + n);
        const float4 v3 = *(const float4*)(xr + (size_t)3 * NN + n);
        a0 += v0.x * m.x + v0.y * m.y + v0.z * m.z + v0.w * m.w;
        a1 += v1.x * m.x + v1.y * m.y + v1.z * m.z + v1.w * m.w;
        a2 += v2.x * m.x + v2.y * m.y + v2.z * m.z + v2.w * m.w;
        a3 += v3.x * m.x + v3.y * m.y + v3.z * m.z + v3.w * m.w;
    }
    #pragma unroll
    for (int off = 32; off; off >>= 1) {
        a0 += __shfl_down(a0, off, 64);
        a1 += __shfl_down(a1, off, 64);
        a2 += __shfl_down(a2, off, 64);
        a3 += __shfl_down(a3, off, 64);
    }
    if (lane == 0) {
        const float s = 1.0f / 2048.0f;
        *(float4*)(out + row0) = make_float4(a0 * s, a1 * s, a2 * s, a3 * s);
    }
}

extern "C" void kernel_launch(void* const* d_in, const int* in_sizes, int n_in,
                              void* d_out, int out_size, void* d_ws, size_t ws_size,
                              hipStream_t stream) {
    const float* x = (const float*)d_in[0];
    float* out = (float*)d_out;
    // ws layout: P = [8][64][4096] fp32 partial scores (8 MB), M = [64][4096]
    // fp32 mask (1 MB).  Every ws word read is written earlier in the same
    // iteration (P by kernel 1, M by kernel 2), so the harness's 0xAA
    // re-poison of d_ws is harmless.
    float* P = (float*)d_ws;
    float* M = P + (size_t)NCHUNK * BB * NN;

    score_partial_kernel<<<dim3(BB * 4, NCHUNK), 256, 0, stream>>>(x, P);
    select_kernel<<<BB, 256, 0, stream>>>(P, M);
    pool_kernel<<<(BB * CC) / 16, 256, 0, stream>>>(x, M, out);
}